// Round 1
// baseline (304.328 us; speedup 1.0000x reference)
//
#include <hip/hip_runtime.h>
#include <hip/hip_bf16.h>

typedef __bf16 bf16;
typedef __attribute__((ext_vector_type(8))) __bf16 bf16x8;
typedef __attribute__((ext_vector_type(4))) __bf16 bf16x4;
typedef __attribute__((ext_vector_type(16))) float f32x16;

#define N_ROWS 16384
#define DIM 256
#define INV_T 14.2857142857f  /* 1/0.07 */

// Kernel 1: L2-normalize rows (fp32 math), emit bf16 matrix to workspace.
// Also zero the output accumulator (d_out is poisoned before every launch).
__global__ void __launch_bounds__(256) normalize_kernel(const float* __restrict__ in,
                                                        bf16* __restrict__ out,
                                                        float* __restrict__ loss_out) {
    if (blockIdx.x == 0 && threadIdx.x == 0) loss_out[0] = 0.0f;
    const int row  = blockIdx.x * 4 + (threadIdx.x >> 6);
    const int lane = threadIdx.x & 63;
    const float4* rp = (const float4*)(in + (size_t)row * DIM);
    float4 v = rp[lane];
    float ss = v.x * v.x + v.y * v.y + v.z * v.z + v.w * v.w;
#pragma unroll
    for (int m = 1; m < 64; m <<= 1) ss += __shfl_xor(ss, m, 64);
    float nrm = fmaxf(sqrtf(ss), 1e-12f);
    float inv = 1.0f / nrm;
    bf16x4 o;
    o[0] = (bf16)(v.x * inv);
    o[1] = (bf16)(v.y * inv);
    o[2] = (bf16)(v.z * inv);
    o[3] = (bf16)(v.w * inv);
    *(bf16x4*)(out + (size_t)row * DIM + lane * 4) = o;
}

// Kernel 2: fused A*A^T + fixed-shift softmax-denominator + loss reduce.
// Block = 512 threads = 8 waves, 64 rows/block. Each wave holds all 64 rows'
// A fragments in registers (2 x 16 x bf16x8 = 128 VGPRs) and walks j-tiles
// strided by 8. C/D layout (32x32x16): col = lane&31,
// row = (reg&3) + 8*(reg>>2) + 4*(lane>>5).
__global__ void __launch_bounds__(512, 2) loss_kernel(const bf16* __restrict__ A,
                                                      float* __restrict__ out) {
    __shared__ float Tsum[64];
    const int wave = threadIdx.x >> 6;
    const int lane = threadIdx.x & 63;
    const int lo = lane & 31, hi = lane >> 5;
    const int rb = blockIdx.x * 64;

    if (threadIdx.x < 64) Tsum[threadIdx.x] = 0.0f;

    // Persistent A fragments for the block's 64 rows.
    bf16x8 a0[16], a1[16];
    {
        const bf16* ap0 = A + (size_t)(rb + lo) * DIM + 8 * hi;
        const bf16* ap1 = ap0 + 32 * DIM;
#pragma unroll
        for (int kk = 0; kk < 16; ++kk) {
            a0[kk] = *(const bf16x8*)(ap0 + 16 * kk);
            a1[kk] = *(const bf16x8*)(ap1 + 16 * kk);
        }
    }

    float s0[16], s1[16];
#pragma unroll
    for (int r = 0; r < 16; ++r) { s0[r] = 0.0f; s1[r] = 0.0f; }

    const float K1 = 20.6099203f;  // 1/(0.07*ln2): exp((dot-1)/T) = exp2(dot*K1 - K1)

    for (int jt = wave; jt < N_ROWS / 32; jt += 8) {
        const bf16* bp = A + (size_t)(jt * 32 + lo) * DIM + 8 * hi;
        f32x16 c0, c1;
#pragma unroll
        for (int r = 0; r < 16; ++r) { c0[r] = 0.0f; c1[r] = 0.0f; }
#pragma unroll
        for (int kk = 0; kk < 16; ++kk) {
            bf16x8 b = *(const bf16x8*)(bp + 16 * kk);
            c0 = __builtin_amdgcn_mfma_f32_32x32x16_bf16(a0[kk], b, c0, 0, 0, 0);
            c1 = __builtin_amdgcn_mfma_f32_32x32x16_bf16(a1[kk], b, c1, 0, 0, 0);
        }
#pragma unroll
        for (int r = 0; r < 16; ++r) {
            s0[r] += __builtin_amdgcn_exp2f(fmaf(c0[r], K1, -K1));
            s1[r] += __builtin_amdgcn_exp2f(fmaf(c1[r], K1, -K1));
        }
    }

    // Reduce over the 32 column-lanes of each half-wave (cols = lane&31).
#pragma unroll
    for (int r = 0; r < 16; ++r) {
        float x0 = s0[r], x1 = s1[r];
#pragma unroll
        for (int m = 1; m < 32; m <<= 1) {
            x0 += __shfl_xor(x0, m, 64);
            x1 += __shfl_xor(x1, m, 64);
        }
        s0[r] = x0; s1[r] = x1;
    }

    __syncthreads();  // Tsum zeroing visible before atomics
    if (lo == 0) {
#pragma unroll
        for (int r = 0; r < 16; ++r) {
            const int ro = (r & 3) + 8 * (r >> 2) + 4 * hi;
            atomicAdd(&Tsum[ro], s0[r]);
            atomicAdd(&Tsum[32 + ro], s1[r]);
        }
    }
    __syncthreads();

    if (threadIdx.x < 64) {
        const int row = rb + threadIdx.x;
        const bf16x8* rp = (const bf16x8*)(A + (size_t)row * DIM);
        float s2 = 0.0f;  // bf16 self-dot: reproduces the MFMA diagonal -> error cancels
#pragma unroll
        for (int i = 0; i < 32; ++i) {
            bf16x8 v = rp[i];
#pragma unroll
            for (int j = 0; j < 8; ++j) {
                float f = (float)v[j];
                s2 = fmaf(f, f, s2);
            }
        }
        // loss_i = (C + log T_i) - s2/T  with C = 1/T
        float contrib = (logf(Tsum[threadIdx.x]) + (1.0f - s2) * INV_T) * (1.0f / (float)N_ROWS);
#pragma unroll
        for (int m = 1; m < 64; m <<= 1) contrib += __shfl_xor(contrib, m, 64);
        if (threadIdx.x == 0) atomicAdd(out, contrib);
    }
}

extern "C" void kernel_launch(void* const* d_in, const int* in_sizes, int n_in,
                              void* d_out, int out_size, void* d_ws, size_t ws_size,
                              hipStream_t stream) {
    const float* emb = (const float*)d_in[0];
    float* out = (float*)d_out;
    bf16* Abf = (bf16*)d_ws;  // 16384*256*2 = 8 MB

    hipLaunchKernelGGL(normalize_kernel, dim3(N_ROWS / 4), dim3(256), 0, stream,
                       emb, Abf, out);
    hipLaunchKernelGGL(loss_kernel, dim3(N_ROWS / 64), dim3(512), 0, stream,
                       Abf, out);
}